// Round 1
// baseline (1013.850 us; speedup 1.0000x reference)
//
#include <hip/hip_runtime.h>
#include <hip/hip_bf16.h>
#include <cstdint>
#include <cstddef>

// Problem constants (from reference): E,D,H1,H2,O,B
#define E_  100
#define D_  2048
#define H1_ 512
#define H2_ 256
#define B_  1024

typedef __bf16 bf16x8 __attribute__((ext_vector_type(8)));
typedef float  f32x4  __attribute__((ext_vector_type(4)));

typedef __attribute__((address_space(1))) void gvoid;
typedef __attribute__((address_space(3))) void lvoid;

__device__ __forceinline__ unsigned short f2bf(float f){
    union { float f; unsigned int u; } x; x.f = f;
    unsigned int r = x.u + 0x7fffu + ((x.u >> 16) & 1u);   // RNE
    return (unsigned short)(r >> 16);
}
__device__ __forceinline__ float bf2f(unsigned int u){
    union { unsigned int i; float f; } x; x.i = u << 16; return x.f;
}

// ---------------- x (and generic) fp32 -> bf16 convert, element-wise ----------------
__global__ __launch_bounds__(256) void cvt_x_kernel(const float* __restrict__ x,
                                                    unsigned short* __restrict__ xb){
    int i = blockIdx.x * 256 + threadIdx.x;
    float4 v = ((const float4*)x)[i];
    ushort4 o;
    o.x = f2bf(v.x); o.y = f2bf(v.y); o.z = f2bf(v.z); o.w = f2bf(v.w);
    ((ushort4*)xb)[i] = o;
}

// ---------------- batched transpose + convert: src fp32 [E][R][C] -> dst bf16 [E][C][R] ----
// 64x64 tiles, XOR-swizzled LDS (dword granularity) so both global sides are coalesced.
__global__ __launch_bounds__(256) void transpose_cvt_kernel(const float* __restrict__ src,
                                                            unsigned short* __restrict__ dst,
                                                            int R, int C){
    __shared__ unsigned int T[64 * 32];     // transposed tile as bf16 pairs, swizzled
    const int e  = blockIdx.z;
    const int r0 = blockIdx.y * 64, c0 = blockIdx.x * 64;
    const float* s = src + (size_t)e * R * C;
    unsigned short* d = dst + (size_t)e * R * C;
    const int t  = threadIdx.x;
    const int cc = (t & 15) * 4;     // col within tile (float4)
    const int rr = t >> 4;           // row 0..15, 4 iterations
    #pragma unroll
    for (int it = 0; it < 4; ++it){
        const int r = rr + it * 16;
        const float4 v = *(const float4*)(s + (size_t)(r0 + r) * C + c0 + cc);
        const float vv[4] = {v.x, v.y, v.z, v.w};
        #pragma unroll
        for (int i = 0; i < 4; ++i){
            const int c  = cc + i;
            const int dw = c * 32 + (((r >> 1)) ^ (c & 31));
            ((unsigned short*)&T[dw])[r & 1] = f2bf(vv[i]);
        }
    }
    __syncthreads();
    const int c  = t >> 2;           // output row (C dim), 0..63
    const int q0 = (t & 3) * 8;      // dword chunk: 8 dwords = 16 bf16 of the R dim
    unsigned int tmp[8];
    #pragma unroll
    for (int j = 0; j < 8; ++j)
        tmp[j] = T[c * 32 + ((q0 + j) ^ (c & 31))];
    unsigned short* drow = d + (size_t)(c0 + c) * R + r0 + q0 * 2;
    ((uint4*)drow)[0] = make_uint4(tmp[0], tmp[1], tmp[2], tmp[3]);
    ((uint4*)drow)[1] = make_uint4(tmp[4], tmp[5], tmp[6], tmp[7]);
}

// ---------------- bf16 MFMA GEMM, B pre-transposed: C[e] = relu(A[e] @ Bt[e]^T + bias[e]) ----
// A: bf16 [.][M][K] (e-stride aEstride elements; 0 => shared A), K fast.
// Bt: bf16 [E][N][K], K fast.  Cout: bf16 [E][M][N].  128x128 tile, 4 waves (2x2), 16x16x32 MFMA.
__global__ __launch_bounds__(256) void gemm_bt_relu(const unsigned short* __restrict__ A,
                                                    long long aEstride,
                                                    const unsigned short* __restrict__ Bt,
                                                    const float* __restrict__ bias,
                                                    unsigned short* __restrict__ Cout,
                                                    int M, int N, int K){
    __shared__ unsigned short As[128 * 32];
    __shared__ unsigned short Bs[128 * 32];
    const int e  = blockIdx.z;
    const int m0 = blockIdx.y * 128, n0 = blockIdx.x * 128;
    const int t = threadIdx.x, lane = t & 63, wid = t >> 6;
    const int wm = wid >> 1, wn = wid & 1;

    const unsigned short* Ae = A + (size_t)e * (size_t)aEstride + (size_t)m0 * K;
    const unsigned short* Be = Bt + (size_t)e * (size_t)N * K + (size_t)n0 * K;

    // staging: chunk = (wid*2+s)*64 + lane ; LDS byte = chunk*16 ; row = chunk/4, k = (chunk%4)*8
    const int ch0 = (wid * 2) * 64 + lane;
    const int r0s = ch0 >> 2, k0s = (ch0 & 3) * 8;
    const int ch1 = ch0 + 64;
    const int r1s = ch1 >> 2, k1s = (ch1 & 3) * 8;

    f32x4 acc[4][4];
    #pragma unroll
    for (int i = 0; i < 4; ++i)
        #pragma unroll
        for (int j = 0; j < 4; ++j) acc[i][j] = 0;

    const int fr = lane & 15;          // row within 16x16 subtile
    const int fk = (lane >> 4) * 8;    // k offset (quad*8)

    for (int k0 = 0; k0 < K; k0 += 32){
        __builtin_amdgcn_global_load_lds((gvoid*)(Ae + (size_t)r0s * K + k0 + k0s),
                                         (lvoid*)(As + (wid * 2 + 0) * 512), 16, 0, 0);
        __builtin_amdgcn_global_load_lds((gvoid*)(Ae + (size_t)r1s * K + k0 + k1s),
                                         (lvoid*)(As + (wid * 2 + 1) * 512), 16, 0, 0);
        __builtin_amdgcn_global_load_lds((gvoid*)(Be + (size_t)r0s * K + k0 + k0s),
                                         (lvoid*)(Bs + (wid * 2 + 0) * 512), 16, 0, 0);
        __builtin_amdgcn_global_load_lds((gvoid*)(Be + (size_t)r1s * K + k0 + k1s),
                                         (lvoid*)(Bs + (wid * 2 + 1) * 512), 16, 0, 0);
        __syncthreads();

        bf16x8 af[4], bf[4];
        #pragma unroll
        for (int i = 0; i < 4; ++i)
            af[i] = *(const bf16x8*)(As + (wm * 64 + i * 16 + fr) * 32 + fk);
        #pragma unroll
        for (int j = 0; j < 4; ++j)
            bf[j] = *(const bf16x8*)(Bs + (wn * 64 + j * 16 + fr) * 32 + fk);
        #pragma unroll
        for (int i = 0; i < 4; ++i)
            #pragma unroll
            for (int j = 0; j < 4; ++j)
                acc[i][j] = __builtin_amdgcn_mfma_f32_16x16x32_bf16(af[i], bf[j], acc[i][j], 0, 0, 0);
        __syncthreads();
    }

    // epilogue: bias + relu, bf16 store. C/D layout: col=lane&15, row=(lane>>4)*4+reg.
    const int row0 = m0 + wm * 64, col0 = n0 + wn * 64;
    const size_t cb = (size_t)e * (size_t)M * N;
    #pragma unroll
    for (int j = 0; j < 4; ++j){
        const int col = col0 + j * 16 + (lane & 15);
        const float bv = bias[(size_t)e * N + col];
        #pragma unroll
        for (int i = 0; i < 4; ++i){
            const int rbase = row0 + i * 16 + (lane >> 4) * 4;
            #pragma unroll
            for (int r = 0; r < 4; ++r){
                float v = acc[i][j][r] + bv;
                v = fmaxf(v, 0.0f);
                Cout[cb + (size_t)(rbase + r) * N + col] = f2bf(v);
            }
        }
    }
}

// ---------------- layer 3: out[b*E+e] = dot(h2[e][b][:], W3[e][:,0]) + b3[e] ----------------
__global__ __launch_bounds__(256) void layer3_kernel(const unsigned short* __restrict__ h2,
                                                     const float* __restrict__ W3,
                                                     const float* __restrict__ b3,
                                                     float* __restrict__ out){
    const int r    = blockIdx.x * 4 + (threadIdx.x >> 6);   // r = e*B + b
    const int lane = threadIdx.x & 63;
    const int e = r >> 10, b = r & 1023;
    const uint2  hv = *(const uint2*)(h2 + (size_t)r * H2_ + lane * 4);
    const float4 wv = *(const float4*)(W3 + (size_t)e * H2_ + lane * 4);
    float sum = bf2f(hv.x & 0xffffu) * wv.x
              + bf2f(hv.x >> 16)     * wv.y
              + bf2f(hv.y & 0xffffu) * wv.z
              + bf2f(hv.y >> 16)     * wv.w;
    #pragma unroll
    for (int o = 32; o > 0; o >>= 1) sum += __shfl_down(sum, o, 64);
    if (lane == 0) out[(size_t)b * E_ + e] = sum + b3[e];
}

extern "C" void kernel_launch(void* const* d_in, const int* in_sizes, int n_in,
                              void* d_out, int out_size, void* d_ws, size_t ws_size,
                              hipStream_t stream){
    const float* x  = (const float*)d_in[0];
    const float* W1 = (const float*)d_in[1];
    const float* b1 = (const float*)d_in[2];
    const float* W2 = (const float*)d_in[3];
    const float* b2 = (const float*)d_in[4];
    const float* W3 = (const float*)d_in[5];
    const float* b3 = (const float*)d_in[6];
    float* out = (float*)d_out;

    char* ws = (char*)d_ws;
    const size_t szW1t = (size_t)E_ * H1_ * D_ * 2;   // 209,715,200 B
    const size_t szW2t = (size_t)E_ * H2_ * H1_ * 2;  //  26,214,400 B
    const size_t szXb  = (size_t)B_ * D_ * 2;         //   4,194,304 B
    unsigned short* W1t = (unsigned short*)(ws);
    unsigned short* W2t = (unsigned short*)(ws + szW1t);
    unsigned short* xb  = (unsigned short*)(ws + szW1t + szW2t);
    unsigned short* h1  = (unsigned short*)(ws + szW1t + szW2t + szXb);
    unsigned short* h2  = (unsigned short*)(ws);      // aliases W1t (dead after gemm1)
    // peak ws use: 209.7 + 26.2 + 4.2 + 104.9 MB = ~345 MB

    cvt_x_kernel<<<(B_ * D_) / (256 * 4), 256, 0, stream>>>(x, xb);
    transpose_cvt_kernel<<<dim3(H1_ / 64, D_ / 64, E_), 256, 0, stream>>>(W1, W1t, D_, H1_);
    transpose_cvt_kernel<<<dim3(H2_ / 64, H1_ / 64, E_), 256, 0, stream>>>(W2, W2t, H1_, H2_);
    gemm_bt_relu<<<dim3(H1_ / 128, B_ / 128, E_), 256, 0, stream>>>(xb, 0, W1t, b1, h1, B_, H1_, D_);
    gemm_bt_relu<<<dim3(H2_ / 128, B_ / 128, E_), 256, 0, stream>>>(h1, (long long)B_ * H1_, W2t, b2, h2, B_, H2_, H1_);
    layer3_kernel<<<(E_ * B_) / 4, 256, 0, stream>>>(h2, W3, b3, out);
}

// Round 2
// 1013.383 us; speedup vs baseline: 1.0005x; 1.0005x over previous
//
#include <hip/hip_runtime.h>
#include <hip/hip_bf16.h>
#include <cstdint>
#include <cstddef>

// Problem constants (from reference): E,D,H1,H2,O,B
#define E_  100
#define D_  2048
#define H1_ 512
#define H2_ 256
#define B_  1024

typedef __bf16 bf16x8 __attribute__((ext_vector_type(8)));
typedef float  f32x4  __attribute__((ext_vector_type(4)));

typedef __attribute__((address_space(1))) void gvoid;
typedef __attribute__((address_space(3))) void lvoid;

__device__ __forceinline__ unsigned short f2bf(float f){
    union { float f; unsigned int u; } x; x.f = f;
    unsigned int r = x.u + 0x7fffu + ((x.u >> 16) & 1u);   // RNE
    return (unsigned short)(r >> 16);
}
__device__ __forceinline__ float bf2f(unsigned int u){
    union { unsigned int i; float f; } x; x.i = u << 16; return x.f;
}

// ---------------- x fp32 -> bf16 convert, element-wise ----------------
__global__ __launch_bounds__(256) void cvt_x_kernel(const float* __restrict__ x,
                                                    unsigned short* __restrict__ xb){
    int i = blockIdx.x * 256 + threadIdx.x;
    float4 v = ((const float4*)x)[i];
    ushort4 o;
    o.x = f2bf(v.x); o.y = f2bf(v.y); o.z = f2bf(v.z); o.w = f2bf(v.w);
    ((ushort4*)xb)[i] = o;
}

// ---------------- batched transpose + convert: src fp32 [E][R][C] -> dst bf16 [E][C][R] ----
// 64x64 tiles. Each thread loads a ROW PAIR and packs 2 bf16 -> 1 dword before the LDS
// write, so all LDS traffic is dword-granular: 8 ds_write_b32 + 8 ds_read_b32 per thread.
// Full XOR swizzle (dw = c*32 + (rp ^ (c&31))) gives max 2-way conflicts (free) both phases.
__global__ __launch_bounds__(256) void transpose_cvt_kernel(const float* __restrict__ src,
                                                            unsigned short* __restrict__ dst,
                                                            int R, int C){
    __shared__ unsigned int T[64 * 32];     // [c][rp] transposed tile as bf16 row-pairs, swizzled
    const int e  = blockIdx.z;
    const int r0 = blockIdx.y * 64, c0 = blockIdx.x * 64;
    const float* s = src + (size_t)e * R * C;
    unsigned short* d = dst + (size_t)e * R * C;
    const int t  = threadIdx.x;
    const int c4 = (t & 15) * 4;     // 4 consecutive cols
    #pragma unroll
    for (int pass = 0; pass < 2; ++pass){
        const int rp = (t >> 4) + pass * 16;       // row pair index 0..31
        const int r  = rp * 2;
        const float4 va = *(const float4*)(s + (size_t)(r0 + r)     * C + c0 + c4);
        const float4 vb = *(const float4*)(s + (size_t)(r0 + r + 1) * C + c0 + c4);
        const float aa[4] = {va.x, va.y, va.z, va.w};
        const float bb[4] = {vb.x, vb.y, vb.z, vb.w};
        #pragma unroll
        for (int i = 0; i < 4; ++i){
            const int c = c4 + i;
            const unsigned int pk = (unsigned int)f2bf(aa[i]) | ((unsigned int)f2bf(bb[i]) << 16);
            T[c * 32 + (rp ^ (c & 31))] = pk;
        }
    }
    __syncthreads();
    const int c  = t >> 2;           // output row (C dim), 0..63
    const int j0 = (t & 3) * 8;      // dword chunk: 8 dwords = 16 bf16 of the R dim
    unsigned int tmp[8];
    #pragma unroll
    for (int j = 0; j < 8; ++j)
        tmp[j] = T[c * 32 + ((j0 + j) ^ (c & 31))];
    unsigned short* drow = d + (size_t)(c0 + c) * R + r0 + j0 * 2;
    ((uint4*)drow)[0] = make_uint4(tmp[0], tmp[1], tmp[2], tmp[3]);
    ((uint4*)drow)[1] = make_uint4(tmp[4], tmp[5], tmp[6], tmp[7]);
}

// ---------------- bf16 MFMA GEMM, B pre-transposed: C[e] = relu(A[e] @ Bt[e]^T + bias[e]) ----
// A: bf16 [.][M][K] (e-stride aEstride elements; 0 => shared A), K fast.
// Bt: bf16 [E][N][K], K fast.  Cout: bf16 [E][M][N].  128x128 tile, 4 waves (2x2), 16x16x32 MFMA.
__global__ __launch_bounds__(256) void gemm_bt_relu(const unsigned short* __restrict__ A,
                                                    long long aEstride,
                                                    const unsigned short* __restrict__ Bt,
                                                    const float* __restrict__ bias,
                                                    unsigned short* __restrict__ Cout,
                                                    int M, int N, int K){
    __shared__ unsigned short As[128 * 32];
    __shared__ unsigned short Bs[128 * 32];
    const int e  = blockIdx.z;
    const int m0 = blockIdx.y * 128, n0 = blockIdx.x * 128;
    const int t = threadIdx.x, lane = t & 63, wid = t >> 6;
    const int wm = wid >> 1, wn = wid & 1;

    const unsigned short* Ae = A + (size_t)e * (size_t)aEstride + (size_t)m0 * K;
    const unsigned short* Be = Bt + (size_t)e * (size_t)N * K + (size_t)n0 * K;

    // staging: chunk = (wid*2+s)*64 + lane ; LDS byte = chunk*16 ; row = chunk/4, k = (chunk%4)*8
    const int ch0 = (wid * 2) * 64 + lane;
    const int r0s = ch0 >> 2, k0s = (ch0 & 3) * 8;
    const int ch1 = ch0 + 64;
    const int r1s = ch1 >> 2, k1s = (ch1 & 3) * 8;

    f32x4 acc[4][4];
    #pragma unroll
    for (int i = 0; i < 4; ++i)
        #pragma unroll
        for (int j = 0; j < 4; ++j) acc[i][j] = 0;

    const int fr = lane & 15;          // row within 16x16 subtile
    const int fk = (lane >> 4) * 8;    // k offset (quad*8)

    for (int k0 = 0; k0 < K; k0 += 32){
        __builtin_amdgcn_global_load_lds((gvoid*)(Ae + (size_t)r0s * K + k0 + k0s),
                                         (lvoid*)(As + (wid * 2 + 0) * 512), 16, 0, 0);
        __builtin_amdgcn_global_load_lds((gvoid*)(Ae + (size_t)r1s * K + k0 + k1s),
                                         (lvoid*)(As + (wid * 2 + 1) * 512), 16, 0, 0);
        __builtin_amdgcn_global_load_lds((gvoid*)(Be + (size_t)r0s * K + k0 + k0s),
                                         (lvoid*)(Bs + (wid * 2 + 0) * 512), 16, 0, 0);
        __builtin_amdgcn_global_load_lds((gvoid*)(Be + (size_t)r1s * K + k0 + k1s),
                                         (lvoid*)(Bs + (wid * 2 + 1) * 512), 16, 0, 0);
        __syncthreads();

        bf16x8 af[4], bf[4];
        #pragma unroll
        for (int i = 0; i < 4; ++i)
            af[i] = *(const bf16x8*)(As + (wm * 64 + i * 16 + fr) * 32 + fk);
        #pragma unroll
        for (int j = 0; j < 4; ++j)
            bf[j] = *(const bf16x8*)(Bs + (wn * 64 + j * 16 + fr) * 32 + fk);
        #pragma unroll
        for (int i = 0; i < 4; ++i)
            #pragma unroll
            for (int j = 0; j < 4; ++j)
                acc[i][j] = __builtin_amdgcn_mfma_f32_16x16x32_bf16(af[i], bf[j], acc[i][j], 0, 0, 0);
        __syncthreads();
    }

    // epilogue: bias + relu, bf16 store. C/D layout: col=lane&15, row=(lane>>4)*4+reg.
    const int row0 = m0 + wm * 64, col0 = n0 + wn * 64;
    const size_t cb = (size_t)e * (size_t)M * N;
    #pragma unroll
    for (int j = 0; j < 4; ++j){
        const int col = col0 + j * 16 + (lane & 15);
        const float bv = bias[(size_t)e * N + col];
        #pragma unroll
        for (int i = 0; i < 4; ++i){
            const int rbase = row0 + i * 16 + (lane >> 4) * 4;
            #pragma unroll
            for (int r = 0; r < 4; ++r){
                float v = acc[i][j][r] + bv;
                v = fmaxf(v, 0.0f);
                Cout[cb + (size_t)(rbase + r) * N + col] = f2bf(v);
            }
        }
    }
}

// ---------------- layer 3: out[b*E+e] = dot(h2[e][b][:], W3[e][:,0]) + b3[e] ----------------
__global__ __launch_bounds__(256) void layer3_kernel(const unsigned short* __restrict__ h2,
                                                     const float* __restrict__ W3,
                                                     const float* __restrict__ b3,
                                                     float* __restrict__ out){
    const int r    = blockIdx.x * 4 + (threadIdx.x >> 6);   // r = e*B + b
    const int lane = threadIdx.x & 63;
    const int e = r >> 10, b = r & 1023;
    const uint2  hv = *(const uint2*)(h2 + (size_t)r * H2_ + lane * 4);
    const float4 wv = *(const float4*)(W3 + (size_t)e * H2_ + lane * 4);
    float sum = bf2f(hv.x & 0xffffu) * wv.x
              + bf2f(hv.x >> 16)     * wv.y
              + bf2f(hv.y & 0xffffu) * wv.z
              + bf2f(hv.y >> 16)     * wv.w;
    #pragma unroll
    for (int o = 32; o > 0; o >>= 1) sum += __shfl_down(sum, o, 64);
    if (lane == 0) out[(size_t)b * E_ + e] = sum + b3[e];
}

extern "C" void kernel_launch(void* const* d_in, const int* in_sizes, int n_in,
                              void* d_out, int out_size, void* d_ws, size_t ws_size,
                              hipStream_t stream){
    const float* x  = (const float*)d_in[0];
    const float* W1 = (const float*)d_in[1];
    const float* b1 = (const float*)d_in[2];
    const float* W2 = (const float*)d_in[3];
    const float* b2 = (const float*)d_in[4];
    const float* W3 = (const float*)d_in[5];
    const float* b3 = (const float*)d_in[6];
    float* out = (float*)d_out;

    char* ws = (char*)d_ws;
    const size_t szW1t = (size_t)E_ * H1_ * D_ * 2;   // 209,715,200 B
    const size_t szW2t = (size_t)E_ * H2_ * H1_ * 2;  //  26,214,400 B
    const size_t szXb  = (size_t)B_ * D_ * 2;         //   4,194,304 B
    unsigned short* W1t = (unsigned short*)(ws);
    unsigned short* W2t = (unsigned short*)(ws + szW1t);
    unsigned short* xb  = (unsigned short*)(ws + szW1t + szW2t);
    unsigned short* h1  = (unsigned short*)(ws + szW1t + szW2t + szXb);
    unsigned short* h2  = (unsigned short*)(ws);      // aliases W1t (dead after gemm1)
    // peak ws use: 209.7 + 26.2 + 4.2 + 104.9 MB = ~345 MB

    cvt_x_kernel<<<(B_ * D_) / (256 * 4), 256, 0, stream>>>(x, xb);
    transpose_cvt_kernel<<<dim3(H1_ / 64, D_ / 64, E_), 256, 0, stream>>>(W1, W1t, D_, H1_);
    transpose_cvt_kernel<<<dim3(H2_ / 64, H1_ / 64, E_), 256, 0, stream>>>(W2, W2t, H1_, H2_);
    gemm_bt_relu<<<dim3(H1_ / 128, B_ / 128, E_), 256, 0, stream>>>(xb, 0, W1t, b1, h1, B_, H1_, D_);
    gemm_bt_relu<<<dim3(H2_ / 128, B_ / 128, E_), 256, 0, stream>>>(h1, (long long)B_ * H1_, W2t, b2, h2, B_, H2_, H1_);
    layer3_kernel<<<(E_ * B_) / 4, 256, 0, stream>>>(h2, W3, b3, out);
}

// Round 3
// 996.659 us; speedup vs baseline: 1.0172x; 1.0168x over previous
//
#include <hip/hip_runtime.h>
#include <hip/hip_bf16.h>
#include <cstdint>
#include <cstddef>

// Problem constants (from reference): E,D,H1,H2,O,B
#define E_  100
#define D_  2048
#define H1_ 512
#define H2_ 256
#define B_  1024

typedef __bf16 bf16x8 __attribute__((ext_vector_type(8)));
typedef float  f32x4  __attribute__((ext_vector_type(4)));

typedef __attribute__((address_space(1))) void gvoid;
typedef __attribute__((address_space(3))) void lvoid;

__device__ __forceinline__ unsigned short f2bf(float f){
    union { float f; unsigned int u; } x; x.f = f;
    unsigned int r = x.u + 0x7fffu + ((x.u >> 16) & 1u);   // RNE
    return (unsigned short)(r >> 16);
}
__device__ __forceinline__ float bf2f(unsigned int u){
    union { unsigned int i; float f; } x; x.i = u << 16; return x.f;
}

// ---------------- x fp32 -> bf16 convert, element-wise ----------------
__global__ __launch_bounds__(256) void cvt_x_kernel(const float* __restrict__ x,
                                                    unsigned short* __restrict__ xb){
    int i = blockIdx.x * 256 + threadIdx.x;
    float4 v = ((const float4*)x)[i];
    ushort4 o;
    o.x = f2bf(v.x); o.y = f2bf(v.y); o.z = f2bf(v.z); o.w = f2bf(v.w);
    ((ushort4*)xb)[i] = o;
}

// ---------------- batched transpose + convert: src fp32 [E][R][C] -> dst bf16 [E][C][R] ----
// 64x64 tiles; row pairs packed to dwords; XOR swizzle -> max 2-way LDS conflicts (free).
__global__ __launch_bounds__(256) void transpose_cvt_kernel(const float* __restrict__ src,
                                                            unsigned short* __restrict__ dst,
                                                            int R, int C){
    __shared__ unsigned int T[64 * 32];     // [c][rp] transposed tile as bf16 row-pairs, swizzled
    const int e  = blockIdx.z;
    const int r0 = blockIdx.y * 64, c0 = blockIdx.x * 64;
    const float* s = src + (size_t)e * R * C;
    unsigned short* d = dst + (size_t)e * R * C;
    const int t  = threadIdx.x;
    const int c4 = (t & 15) * 4;     // 4 consecutive cols
    #pragma unroll
    for (int pass = 0; pass < 2; ++pass){
        const int rp = (t >> 4) + pass * 16;       // row pair index 0..31
        const int r  = rp * 2;
        const float4 va = *(const float4*)(s + (size_t)(r0 + r)     * C + c0 + c4);
        const float4 vb = *(const float4*)(s + (size_t)(r0 + r + 1) * C + c0 + c4);
        const float aa[4] = {va.x, va.y, va.z, va.w};
        const float bb[4] = {vb.x, vb.y, vb.z, vb.w};
        #pragma unroll
        for (int i = 0; i < 4; ++i){
            const int c = c4 + i;
            const unsigned int pk = (unsigned int)f2bf(aa[i]) | ((unsigned int)f2bf(bb[i]) << 16);
            T[c * 32 + (rp ^ (c & 31))] = pk;
        }
    }
    __syncthreads();
    const int c  = t >> 2;           // output row (C dim), 0..63
    const int j0 = (t & 3) * 8;      // dword chunk: 8 dwords = 16 bf16 of the R dim
    unsigned int tmp[8];
    #pragma unroll
    for (int j = 0; j < 8; ++j)
        tmp[j] = T[c * 32 + ((j0 + j) ^ (c & 31))];
    unsigned short* drow = d + (size_t)(c0 + c) * R + r0 + j0 * 2;
    ((uint4*)drow)[0] = make_uint4(tmp[0], tmp[1], tmp[2], tmp[3]);
    ((uint4*)drow)[1] = make_uint4(tmp[4], tmp[5], tmp[6], tmp[7]);
}

// ---------------- bf16 MFMA GEMM, B pre-transposed: C[e] = relu(A[e] @ Bt[e]^T + bias[e]) ----
// A: bf16 [.][M][K] (e-stride aEstride elements; 0 => shared A), K fast.
// Bt: bf16 [E][N][K], K fast.  Cout: bf16 [E][M][N].  128x128 tile, 4 waves (2x2), 16x16x32 MFMA.
// LDS k-chunk XOR swizzle: global k-chunk (c ^ ((row>>1)&3)) goes to LDS slot c, so the
// ds_read_b128 fragment reads land 2-way per bank-group (free) instead of 8-way.
__global__ __launch_bounds__(256) void gemm_bt_relu(const unsigned short* __restrict__ A,
                                                    long long aEstride,
                                                    const unsigned short* __restrict__ Bt,
                                                    const float* __restrict__ bias,
                                                    unsigned short* __restrict__ Cout,
                                                    int M, int N, int K){
    __shared__ unsigned short As[128 * 32];
    __shared__ unsigned short Bs[128 * 32];
    const int e  = blockIdx.z;
    const int m0 = blockIdx.y * 128, n0 = blockIdx.x * 128;
    const int t = threadIdx.x, lane = t & 63, wid = t >> 6;
    const int wm = wid >> 1, wn = wid & 1;

    const unsigned short* Ae = A + (size_t)e * (size_t)aEstride + (size_t)m0 * K;
    const unsigned short* Be = Bt + (size_t)e * (size_t)N * K + (size_t)n0 * K;

    // staging: chunk ch = wid*128 + s*64 + lane ; LDS byte = ch*16 ; row = ch>>2
    // global k-chunk for this slot: (ch&3) ^ ((row>>1)&3)  (XOR swizzle)
    const int ch0 = wid * 128 + lane;
    const int r0s = ch0 >> 2, k0s = (((ch0 & 3) ^ ((ch0 >> 3) & 3)) * 8);
    const int ch1 = ch0 + 64;
    const int r1s = ch1 >> 2, k1s = (((ch1 & 3) ^ ((ch1 >> 3) & 3)) * 8);

    f32x4 acc[4][4];
    #pragma unroll
    for (int i = 0; i < 4; ++i)
        #pragma unroll
        for (int j = 0; j < 4; ++j) acc[i][j] = 0;

    const int fr  = lane & 15;                  // row within 16x16 subtile
    const int fc  = lane >> 4;                  // k chunk 0..3 (8 shorts each)
    const int fsw = (fr >> 1) & 3;              // row swizzle selector
    const int fo  = ((fc ^ fsw) * 8);           // element offset within LDS row

    for (int k0 = 0; k0 < K; k0 += 32){
        __builtin_amdgcn_global_load_lds((gvoid*)(Ae + (size_t)r0s * K + k0 + k0s),
                                         (lvoid*)(As + (wid * 2 + 0) * 512), 16, 0, 0);
        __builtin_amdgcn_global_load_lds((gvoid*)(Ae + (size_t)r1s * K + k0 + k1s),
                                         (lvoid*)(As + (wid * 2 + 1) * 512), 16, 0, 0);
        __builtin_amdgcn_global_load_lds((gvoid*)(Be + (size_t)r0s * K + k0 + k0s),
                                         (lvoid*)(Bs + (wid * 2 + 0) * 512), 16, 0, 0);
        __builtin_amdgcn_global_load_lds((gvoid*)(Be + (size_t)r1s * K + k0 + k1s),
                                         (lvoid*)(Bs + (wid * 2 + 1) * 512), 16, 0, 0);
        __syncthreads();

        bf16x8 af[4], bf[4];
        #pragma unroll
        for (int i = 0; i < 4; ++i)
            af[i] = *(const bf16x8*)(As + (wm * 64 + i * 16 + fr) * 32 + fo);
        #pragma unroll
        for (int j = 0; j < 4; ++j)
            bf[j] = *(const bf16x8*)(Bs + (wn * 64 + j * 16 + fr) * 32 + fo);
        #pragma unroll
        for (int i = 0; i < 4; ++i)
            #pragma unroll
            for (int j = 0; j < 4; ++j)
                acc[i][j] = __builtin_amdgcn_mfma_f32_16x16x32_bf16(af[i], bf[j], acc[i][j], 0, 0, 0);
        __syncthreads();
    }

    // epilogue: bias + relu, bf16 store. C/D layout: col=lane&15, row=(lane>>4)*4+reg.
    const int row0 = m0 + wm * 64, col0 = n0 + wn * 64;
    const size_t cb = (size_t)e * (size_t)M * N;
    #pragma unroll
    for (int j = 0; j < 4; ++j){
        const int col = col0 + j * 16 + (lane & 15);
        const float bv = bias[(size_t)e * N + col];
        #pragma unroll
        for (int i = 0; i < 4; ++i){
            const int rbase = row0 + i * 16 + (lane >> 4) * 4;
            #pragma unroll
            for (int r = 0; r < 4; ++r){
                float v = acc[i][j][r] + bv;
                v = fmaxf(v, 0.0f);
                Cout[cb + (size_t)(rbase + r) * N + col] = f2bf(v);
            }
        }
    }
}

// ---------------- layer 3: out[b*E+e] = dot(h2[e][b][:], W3[e][:,0]) + b3[e] ----------------
// One wave per 16 consecutive rows (same e): W3 fragment + bias loaded once per wave.
__global__ __launch_bounds__(256) void layer3_kernel(const unsigned short* __restrict__ h2,
                                                     const float* __restrict__ W3,
                                                     const float* __restrict__ b3,
                                                     float* __restrict__ out){
    const int w     = blockIdx.x * 4 + (threadIdx.x >> 6);   // wave id
    const int lane  = threadIdx.x & 63;
    const int rbase = w * 16;                                // 16 rows, same e (1024%16==0)
    const int e     = rbase >> 10;
    const float4 wv = *(const float4*)(W3 + (size_t)e * H2_ + lane * 4);
    const float  bv = b3[e];
    #pragma unroll
    for (int i = 0; i < 16; ++i){
        const int r = rbase + i;
        const uint2 hv = *(const uint2*)(h2 + (size_t)r * H2_ + lane * 4);
        float sum = bf2f(hv.x & 0xffffu) * wv.x
                  + bf2f(hv.x >> 16)     * wv.y
                  + bf2f(hv.y & 0xffffu) * wv.z
                  + bf2f(hv.y >> 16)     * wv.w;
        #pragma unroll
        for (int o = 32; o > 0; o >>= 1) sum += __shfl_down(sum, o, 64);
        if (lane == 0) out[(size_t)(r & 1023) * E_ + e] = sum + bv;
    }
}

extern "C" void kernel_launch(void* const* d_in, const int* in_sizes, int n_in,
                              void* d_out, int out_size, void* d_ws, size_t ws_size,
                              hipStream_t stream){
    const float* x  = (const float*)d_in[0];
    const float* W1 = (const float*)d_in[1];
    const float* b1 = (const float*)d_in[2];
    const float* W2 = (const float*)d_in[3];
    const float* b2 = (const float*)d_in[4];
    const float* W3 = (const float*)d_in[5];
    const float* b3 = (const float*)d_in[6];
    float* out = (float*)d_out;

    char* ws = (char*)d_ws;
    const size_t szW1t = (size_t)E_ * H1_ * D_ * 2;   // 209,715,200 B
    const size_t szW2t = (size_t)E_ * H2_ * H1_ * 2;  //  26,214,400 B
    const size_t szXb  = (size_t)B_ * D_ * 2;         //   4,194,304 B
    unsigned short* W1t = (unsigned short*)(ws);
    unsigned short* W2t = (unsigned short*)(ws + szW1t);
    unsigned short* xb  = (unsigned short*)(ws + szW1t + szW2t);
    unsigned short* h1  = (unsigned short*)(ws + szW1t + szW2t + szXb);
    unsigned short* h2  = (unsigned short*)(ws);      // aliases W1t (dead after gemm1)
    // peak ws use: 209.7 + 26.2 + 4.2 + 104.9 MB = ~345 MB

    cvt_x_kernel<<<(B_ * D_) / (256 * 4), 256, 0, stream>>>(x, xb);
    transpose_cvt_kernel<<<dim3(H1_ / 64, D_ / 64, E_), 256, 0, stream>>>(W1, W1t, D_, H1_);
    transpose_cvt_kernel<<<dim3(H2_ / 64, H1_ / 64, E_), 256, 0, stream>>>(W2, W2t, H1_, H2_);
    gemm_bt_relu<<<dim3(H1_ / 128, B_ / 128, E_), 256, 0, stream>>>(xb, 0, W1t, b1, h1, B_, H1_, D_);
    gemm_bt_relu<<<dim3(H2_ / 128, B_ / 128, E_), 256, 0, stream>>>(h1, (long long)B_ * H1_, W2t, b2, h2, B_, H2_, H1_);
    layer3_kernel<<<(E_ * B_) / 64, 256, 0, stream>>>(h2, W3, b3, out);
}